// Round 19
// baseline (847.537 us; speedup 1.0000x reference)
//
#include <hip/hip_runtime.h>
#include <hip/hip_fp16.h>

#define IN_DIM 128
#define NCLS 40
#define AS_STRIDE 136   // halves; 272 B row stride
#define SLICE_MAX 12544 // max nodes per 1/8 slice (N<=100352)
#define HB 32           // edge chunks (blocks per slice)
#define ECHUNK 4096     // staged csr entries (16 KB LDS)

typedef int ivec4 __attribute__((ext_vector_type(4)));

__device__ __forceinline__ int ntl_i(const int* p) { return __builtin_nontemporal_load(p); }
__device__ __forceinline__ int4 ntl_i4(const int4* p) {
    ivec4 v = __builtin_nontemporal_load((const ivec4*)p);
    return make_int4(v.x, v.y, v.z, v.w);
}

// ---------------- sliced LDS histogram (no global atomics) ----------------

__global__ __launch_bounds__(256) void hist_sliced(const int* __restrict__ idx, int* __restrict__ staging,
                                                   int E, int N) {
    __shared__ int hist[SLICE_MAX];
    int bid = blockIdx.x;
    int slice = bid & 7;
    int b = bid >> 3;
    int chunkN = (N + 7) >> 3;
    int lo = slice * chunkN;
    int hi = min(lo + chunkN, N);
    int t = threadIdx.x;
    for (int i = t; i < SLICE_MAX; i += 256) hist[i] = 0;
    __syncthreads();
    int ce = (E + HB - 1) / HB;
    int e0 = b * ce, e1 = min(e0 + ce, E);
    int nv = (e1 - e0) >> 2;
    const int4* iv = (const int4*)(idx + e0);
    for (int k = t; k < nv; k += 256) {
        int4 d = ntl_i4(iv + k);
        if (d.x >= lo && d.x < hi) atomicAdd(&hist[d.x - lo], 1);
        if (d.y >= lo && d.y < hi) atomicAdd(&hist[d.y - lo], 1);
        if (d.z >= lo && d.z < hi) atomicAdd(&hist[d.z - lo], 1);
        if (d.w >= lo && d.w < hi) atomicAdd(&hist[d.w - lo], 1);
    }
    for (int e = e0 + nv * 4 + t; e < e1; e += 256) {
        int d = idx[e];
        if (d >= lo && d < hi) atomicAdd(&hist[d - lo], 1);
    }
    __syncthreads();
    int* sp = staging + (size_t)(slice * HB + b) * SLICE_MAX;
    for (int i = t; i < chunkN; i += 256) sp[i] = hist[i];
}

// ---------------- reduce staging -> degree; optionally write back exclusive prefix ----------

template<int SCANBACK>
__global__ __launch_bounds__(256) void reduce_staging(int* __restrict__ staging, int* __restrict__ deg, int N) {
    int i = blockIdx.x * 256 + threadIdx.x;
    if (i >= N) return;
    int chunkN = (N + 7) >> 3;
    int slice = i / chunkN;
    int li = i - slice * chunkN;
    int* basep = staging + (size_t)slice * HB * SLICE_MAX + li;
    int acc = 0;
#pragma unroll
    for (int b = 0; b < HB; ++b) {
        int* p = basep + (size_t)b * SLICE_MAX;
        int v = *p;
        if (SCANBACK) *p = acc;
        acc += v;
    }
    deg[i] = acc;
}

__global__ __launch_bounds__(256) void norm_kernel(const int* __restrict__ ds, const int* __restrict__ dd,
                                                   float* __restrict__ ns, float* __restrict__ nd, int N) {
    int i = blockIdx.x * 256 + threadIdx.x;
    if (i < N) {
        ns[i] = ds[i] > 0 ? rsqrtf((float)ds[i]) : 0.f;
        nd[i] = dd[i] > 0 ? rsqrtf((float)dd[i]) : 0.f;
    }
}

// ---------------- exclusive scan of in-degrees -> row starts cursor[0..N] ----------------

__global__ __launch_bounds__(256) void scan_partial(const int* __restrict__ dd, int* __restrict__ bsums, int N) {
    __shared__ int sd[256];
    int t = threadIdx.x;
    int base = blockIdx.x * 1024 + t * 4;
    int s = 0;
#pragma unroll
    for (int k = 0; k < 4; ++k) { int i = base + k; if (i < N) s += dd[i]; }
    sd[t] = s;
    __syncthreads();
    for (int off = 128; off > 0; off >>= 1) {
        if (t < off) sd[t] += sd[t + off];
        __syncthreads();
    }
    if (t == 0) bsums[blockIdx.x] = sd[0];
}

__global__ __launch_bounds__(128) void scan_bsums(int* __restrict__ bsums, int nb) {
    __shared__ int sd[128];
    __shared__ int carry_s;
    int t = threadIdx.x;
    if (t == 0) carry_s = 0;
    __syncthreads();
    for (int base = 0; base < nb; base += 128) {
        int i = base + t;
        int orig = (i < nb) ? bsums[i] : 0;
        sd[t] = orig;
        __syncthreads();
        for (int off = 1; off < 128; off <<= 1) {
            int u = (t >= off) ? sd[t - off] : 0;
            __syncthreads();
            sd[t] += u;
            __syncthreads();
        }
        int carry = carry_s;
        if (i < nb) bsums[i] = carry + sd[t] - orig;   // exclusive
        __syncthreads();
        if (t == 127) carry_s = carry + sd[127];
        __syncthreads();
    }
}

__global__ __launch_bounds__(256) void scan_final(const int* __restrict__ dd, const int* __restrict__ bsums,
                                                  int* __restrict__ cursor, int N) {
    __shared__ int sd[256];
    int t = threadIdx.x;
    int base = blockIdx.x * 1024 + t * 4;
    int v[4]; int s = 0;
#pragma unroll
    for (int k = 0; k < 4; ++k) { int i = base + k; v[k] = (i < N) ? dd[i] : 0; s += v[k]; }
    sd[t] = s;
    __syncthreads();
    for (int off = 1; off < 256; off <<= 1) {
        int u = (t >= off) ? sd[t - off] : 0;
        __syncthreads();
        sd[t] += u;
        __syncthreads();
    }
    int excl = sd[t] - s + bsums[blockIdx.x];
#pragma unroll
    for (int k = 0; k < 4; ++k) {
        int i = base + k;
        if (i < N) {
            cursor[i] = excl;       // exclusive row start
            excl += v[k];
            if (i == N - 1) cursor[N] = excl;
        }
    }
}

// ---------------- CSR fill: LDS cursors (rowstart + staged prefix), no global atomics -------

__global__ __launch_bounds__(256) void fill_noatomic(const int* __restrict__ src, const int* __restrict__ dst,
                                                     const int* __restrict__ rowstart, const int* __restrict__ staging,
                                                     int* __restrict__ csr, int E, int N) {
    __shared__ int cur[SLICE_MAX];
    int bid = blockIdx.x;
    int slice = bid & 7;
    int b = bid >> 3;
    int chunkN = (N + 7) >> 3;
    int lo = slice * chunkN;
    int hi = min(lo + chunkN, N);
    int t = threadIdx.x;
    const int* sp = staging + (size_t)(slice * HB + b) * SLICE_MAX;
    for (int i = t; i < chunkN; i += 256) cur[i] = rowstart[lo + i] + sp[i];
    __syncthreads();
    int ce = (E + HB - 1) / HB;
    int e0 = b * ce, e1 = min(e0 + ce, E);
    int nv = (e1 - e0) >> 2;
    const int4* dv4 = (const int4*)(dst + e0);
    const int4* sv4 = (const int4*)(src + e0);
    for (int k = t; k < nv; k += 256) {
        int4 d = ntl_i4(dv4 + k);
        int4 sv = ntl_i4(sv4 + k);
        if (d.x >= lo && d.x < hi) csr[atomicAdd(&cur[d.x - lo], 1)] = sv.x;
        if (d.y >= lo && d.y < hi) csr[atomicAdd(&cur[d.y - lo], 1)] = sv.y;
        if (d.z >= lo && d.z < hi) csr[atomicAdd(&cur[d.z - lo], 1)] = sv.z;
        if (d.w >= lo && d.w < hi) csr[atomicAdd(&cur[d.w - lo], 1)] = sv.w;
    }
    for (int e = e0 + nv * 4 + t; e < e1; e += 256) {
        int d = dst[e];
        if (d >= lo && d < hi) csr[atomicAdd(&cur[d - lo], 1)] = src[e];
    }
}

// ---------------- helpers ----------------

__device__ __forceinline__ float4 zero4() { return make_float4(0.f, 0.f, 0.f, 0.f); }

__device__ __forceinline__ void fma4(float4& acc, float s, const float4& wv) {
    acc.x = fmaf(s, wv.x, acc.x);
    acc.y = fmaf(s, wv.y, acc.y);
    acc.z = fmaf(s, wv.z, acc.z);
    acc.w = fmaf(s, wv.w, acc.w);
}

__device__ __forceinline__ void add_h8(float4& a0, float4& a1, const int4& v) {
    const __half2* h = (const __half2*)&v;
    float2 f0 = __half22float2(h[0]);
    float2 f1 = __half22float2(h[1]);
    float2 f2 = __half22float2(h[2]);
    float2 f3 = __half22float2(h[3]);
    a0.x += f0.x; a0.y += f0.y; a0.z += f1.x; a0.w += f1.y;
    a1.x += f2.x; a1.y += f2.y; a1.z += f3.x; a1.w += f3.y;
}

__device__ __forceinline__ int4 pack_h8(const float4& o0, const float4& o1) {
    int4 p;
    __half2* ph = (__half2*)&p;
    ph[0] = __float22half2_rn(make_float2(o0.x, o0.y));
    ph[1] = __float22half2_rn(make_float2(o0.z, o0.w));
    ph[2] = __float22half2_rn(make_float2(o1.x, o1.y));
    ph[3] = __float22half2_rn(make_float2(o1.z, o1.w));
    return p;
}

// ---------------- prescale into slabs: slab s holds halves [16s,16s+16) of every row ----------

__global__ __launch_bounds__(256) void prescale_kernel(const float* __restrict__ x, const float* __restrict__ ns,
                                                       __half* __restrict__ xs, int N) {
    int tid = blockIdx.x * 256 + threadIdx.x;     // over 16N int4s, slab-major
    if (tid >= N * 16) return;
    int s = tid / (2 * N);
    int rem = tid - s * 2 * N;
    int n = rem >> 1;
    int h = rem & 1;
    float sc = ns[n];
    const float4* xp = (const float4*)x + (size_t)n * 32 + (s * 2 + h) * 2;
    float4 v0 = xp[0], v1 = xp[1];
    v0.x *= sc; v0.y *= sc; v0.z *= sc; v0.w *= sc;
    v1.x *= sc; v1.y *= sc; v1.z *= sc; v1.w *= sc;
    ((int4*)xs)[tid] = pack_h8(v0, v1);
}

// ---------------- slab SpMM: edge-balanced lane pairs, LDS accumulate ----------------
// grid = ceil(N/128)*8; slice = bid&7 (XCD-pinned 3.2 MB slab). Block's 128 rows own a
// contiguous csr span; stage it in LDS; each lane-pair walks a contiguous 1/128 of the
// span (no degree divergence), register-accumulates per row-run, flushes to LDS fp32
// accumulator via atomicAdd on row change. Block writes the 128x32B tile at the end.

__global__ __launch_bounds__(256) void spmm16s(const __half* __restrict__ xs, const int* __restrict__ csr,
                                               const int* __restrict__ cursor, __half* __restrict__ as_, int N) {
    __shared__ int eidx[ECHUNK];       // 16 KB
    __shared__ float accs[128 * 16];   // 8 KB
    __shared__ int rp[129];
    int bid = blockIdx.x;
    int slice = bid & 7;
    int rb = bid >> 3;
    int row0 = rb * 128;
    int t = threadIdx.x;
    int p = t >> 1;        // pair 0..127
    int h = t & 1;         // 16B half
    const int4* xi = (const int4*)xs + (size_t)slice * N * 2;

    if (t <= 128) rp[t] = cursor[min(row0 + t, N)];
    {
        float4* az = (float4*)accs;
        for (int i = t; i < 128 * 4; i += 256) az[i] = zero4();
    }
    __syncthreads();

    int estart = rp[0];
    int eend = rp[128];
    for (int cb = estart; cb < eend; cb += ECHUNK) {
        int cn = min(ECHUNK, eend - cb);
        for (int i = t; i < cn; i += 256) eidx[i] = ntl_i(csr + cb + i);
        __syncthreads();
        int len = (cn + 127) >> 7;
        int e0 = cb + p * len;
        int e1 = min(e0 + len, cb + cn);
        if (e0 < e1) {
            // binary search: largest row with rp[row] <= e0
            int lo = 0, hi = 128;
            while (hi - lo > 1) { int mid = (lo + hi) >> 1; if (rp[mid] <= e0) lo = mid; else hi = mid; }
            int cur = lo;
            int nxt = rp[cur + 1];
            float4 a0 = zero4(), a1 = zero4();
            for (int e = e0; e < e1; ++e) {
                while (e >= nxt) {
                    float* dp = &accs[cur * 16 + h * 8];
                    atomicAdd(dp + 0, a0.x); atomicAdd(dp + 1, a0.y);
                    atomicAdd(dp + 2, a0.z); atomicAdd(dp + 3, a0.w);
                    atomicAdd(dp + 4, a1.x); atomicAdd(dp + 5, a1.y);
                    atomicAdd(dp + 6, a1.z); atomicAdd(dp + 7, a1.w);
                    a0 = zero4(); a1 = zero4();
                    ++cur; nxt = rp[cur + 1];
                }
                int4 v = xi[(size_t)eidx[e - cb] * 2 + h];
                add_h8(a0, a1, v);
            }
            float* dp = &accs[cur * 16 + h * 8];
            atomicAdd(dp + 0, a0.x); atomicAdd(dp + 1, a0.y);
            atomicAdd(dp + 2, a0.z); atomicAdd(dp + 3, a0.w);
            atomicAdd(dp + 4, a1.x); atomicAdd(dp + 5, a1.y);
            atomicAdd(dp + 6, a1.z); atomicAdd(dp + 7, a1.w);
        }
        __syncthreads();
    }

    // write out: pair p -> row row0+p, half h
    int r = row0 + p;
    if (r < N) {
        const float* sp2 = &accs[p * 16 + h * 8];
        float4 o0 = *(const float4*)(sp2 + 0);
        float4 o1 = *(const float4*)(sp2 + 4);
        ((int4*)as_)[(size_t)slice * N * 2 + (size_t)r * 2 + h] = pack_h8(o0, o1);
    }
}

// ---------------- GEMM 128(fp16 slab agg) -> 128, epilogue acc*nd+bias, relu, (*ns) -> slabs --

template<int SCALE_NS>
__global__ __launch_bounds__(256, 6) void gemm128h(const __half* __restrict__ agg, const float* __restrict__ nd,
                                                   const float* __restrict__ ns, const float* __restrict__ W,
                                                   const float* __restrict__ bias, __half* __restrict__ out, int N) {
    __shared__ __half As[64 * AS_STRIDE];
    int t = threadIdx.x;
    int row0 = blockIdx.x * 64;

#pragma unroll
    for (int i = 0; i < 4; ++i) {
        int idx = t + 256 * i;          // 0..1023
        int s = idx >> 7;
        int rem = idx & 127;
        int r = rem >> 1;
        int h = rem & 1;
        int gr = row0 + r;
        int4 v = make_int4(0, 0, 0, 0);
        if (gr < N) v = ((const int4*)agg)[(size_t)s * N * 2 + (size_t)gr * 2 + h];
        *(int4*)&As[r * AS_STRIDE + (s * 2 + h) * 8] = v;
    }
    __syncthreads();

    int rg = t >> 4;
    int cgp = t & 15;
    int rbase = rg * 4;
    const float4* Wg = (const float4*)W;
    float4 acc[4][2];
#pragma unroll
    for (int m = 0; m < 4; ++m) { acc[m][0] = zero4(); acc[m][1] = zero4(); }
#pragma unroll 2
    for (int k4 = 0; k4 < 32; ++k4) {
        int k0 = k4 * 4;
        float4 a[4];
#pragma unroll
        for (int m = 0; m < 4; ++m) {
            uint2 raw = *(const uint2*)&As[(rbase + m) * AS_STRIDE + k0];
            const __half2* hp = (const __half2*)&raw;
            float2 f0 = __half22float2(hp[0]);
            float2 f1 = __half22float2(hp[1]);
            a[m] = make_float4(f0.x, f0.y, f1.x, f1.y);
        }
        float4 w[4][2];
#pragma unroll
        for (int j = 0; j < 4; ++j) {
            w[j][0] = Wg[(k0 + j) * 32 + cgp * 2 + 0];
            w[j][1] = Wg[(k0 + j) * 32 + cgp * 2 + 1];
        }
#pragma unroll
        for (int m = 0; m < 4; ++m) {
            fma4(acc[m][0], a[m].x, w[0][0]); fma4(acc[m][1], a[m].x, w[0][1]);
            fma4(acc[m][0], a[m].y, w[1][0]); fma4(acc[m][1], a[m].y, w[1][1]);
            fma4(acc[m][0], a[m].z, w[2][0]); fma4(acc[m][1], a[m].z, w[2][1]);
            fma4(acc[m][0], a[m].w, w[3][0]); fma4(acc[m][1], a[m].w, w[3][1]);
        }
    }

    float4 bb0 = ((const float4*)bias)[cgp * 2 + 0];
    float4 bb1 = ((const float4*)bias)[cgp * 2 + 1];
    int os = cgp >> 1, oh = cgp & 1;
#pragma unroll
    for (int m = 0; m < 4; ++m) {
        int gr = row0 + rbase + m;
        if (gr < N) {
            float ndr = nd[gr];
            float4 o0, o1;
            o0.x = fmaxf(fmaf(acc[m][0].x, ndr, bb0.x), 0.f);
            o0.y = fmaxf(fmaf(acc[m][0].y, ndr, bb0.y), 0.f);
            o0.z = fmaxf(fmaf(acc[m][0].z, ndr, bb0.z), 0.f);
            o0.w = fmaxf(fmaf(acc[m][0].w, ndr, bb0.w), 0.f);
            o1.x = fmaxf(fmaf(acc[m][1].x, ndr, bb1.x), 0.f);
            o1.y = fmaxf(fmaf(acc[m][1].y, ndr, bb1.y), 0.f);
            o1.z = fmaxf(fmaf(acc[m][1].z, ndr, bb1.z), 0.f);
            o1.w = fmaxf(fmaf(acc[m][1].w, ndr, bb1.w), 0.f);
            if (SCALE_NS) {
                float s = ns[gr];
                o0.x *= s; o0.y *= s; o0.z *= s; o0.w *= s;
                o1.x *= s; o1.y *= s; o1.z *= s; o1.w *= s;
            }
            ((int4*)out)[(size_t)os * N * 2 + (size_t)gr * 2 + oh] = pack_h8(o0, o1);
        }
    }
}

// ---------------- final GEMM: agg2(slab fp16) -> 40, epilogue *nd + b2 -> fp32 out ----------

__global__ __launch_bounds__(256) void gemm40_final(const __half* __restrict__ A, const float* __restrict__ nd,
                                                    const float* __restrict__ W, const float* __restrict__ b2,
                                                    float* __restrict__ out, int N) {
    __shared__ float Ws[128 * NCLS];   // 20 KB
    __shared__ float As[32 * 132];     // 16.5 KB
    int t = threadIdx.x;
    int row0 = blockIdx.x * 32;

#pragma unroll
    for (int i = 0; i < 5; ++i) {
        int idx = t + 256 * i;
        ((float4*)Ws)[idx] = ((const float4*)W)[idx];
    }
#pragma unroll
    for (int i = 0; i < 2; ++i) {
        int idx = t + 256 * i;        // 0..511
        int s = idx >> 6;
        int rem = idx & 63;
        int r = rem >> 1;
        int h = rem & 1;
        int gr = row0 + r;
        int4 v = make_int4(0, 0, 0, 0);
        if (gr < N) v = ((const int4*)A)[(size_t)s * N * 2 + (size_t)gr * 2 + h];
        const __half2* hh = (const __half2*)&v;
        float2 f0 = __half22float2(hh[0]);
        float2 f1 = __half22float2(hh[1]);
        float2 f2 = __half22float2(hh[2]);
        float2 f3 = __half22float2(hh[3]);
        float* dp = &As[r * 132 + (s * 2 + h) * 8];
        dp[0] = f0.x; dp[1] = f0.y; dp[2] = f1.x; dp[3] = f1.y;
        dp[4] = f2.x; dp[5] = f2.y; dp[6] = f3.x; dp[7] = f3.y;
    }
    __syncthreads();

    int row = t >> 3;
    int cg = t & 7;
    float acc[5] = {0.f, 0.f, 0.f, 0.f, 0.f};
#pragma unroll 2
    for (int k4 = 0; k4 < 32; ++k4) {
        float4 a = *(const float4*)&As[row * 132 + k4 * 4];
#pragma unroll
        for (int j = 0; j < 4; ++j) {
            float av = (j == 0) ? a.x : (j == 1) ? a.y : (j == 2) ? a.z : a.w;
            const float* wp = &Ws[(k4 * 4 + j) * NCLS + cg * 5];
            acc[0] = fmaf(av, wp[0], acc[0]);
            acc[1] = fmaf(av, wp[1], acc[1]);
            acc[2] = fmaf(av, wp[2], acc[2]);
            acc[3] = fmaf(av, wp[3], acc[3]);
            acc[4] = fmaf(av, wp[4], acc[4]);
        }
    }
    int gr = row0 + row;
    if (gr < N) {
        float s = nd[gr];
        const float* bp = b2 + cg * 5;
        float* yp = out + (size_t)gr * NCLS + cg * 5;
        yp[0] = fmaf(acc[0], s, bp[0]);
        yp[1] = fmaf(acc[1], s, bp[1]);
        yp[2] = fmaf(acc[2], s, bp[2]);
        yp[3] = fmaf(acc[3], s, bp[3]);
        yp[4] = fmaf(acc[4], s, bp[4]);
    }
}

extern "C" void kernel_launch(void* const* d_in, const int* in_sizes, int n_in,
                              void* d_out, int out_size, void* d_ws, size_t ws_size,
                              hipStream_t stream) {
    const float* x  = (const float*)d_in[0];
    const int* src  = (const int*)d_in[1];
    const int* dst  = (const int*)d_in[2];
    const float* W0 = (const float*)d_in[3];
    const float* b0 = (const float*)d_in[4];
    const float* W1 = (const float*)d_in[5];
    const float* b1 = (const float*)d_in[6];
    const float* W2 = (const float*)d_in[7];
    const float* b2 = (const float*)d_in[8];
    float* out = (float*)d_out;

    int N = in_sizes[0] / IN_DIM;
    int E = in_sizes[1];

    float* base = (float*)d_ws;
    float* ns   = base;                       // N
    float* ndn  = base + (size_t)N;           // N
    int* dsg    = (int*)(base + 2 * (size_t)N);
    int* ddg    = dsg + (size_t)N;
    int* cursor = ddg + (size_t)N;            // N+1
    int* bsums  = cursor + (size_t)N + 1;     // 1024
    int* csr    = bsums + 1024;               // E
    __half* B0  = (__half*)(csr + (size_t)E); // N x 128 halves (slabs)
    __half* B1  = B0 + (size_t)N * 128;       // N x 128 halves (slabs)
    __half* B2  = B1 + (size_t)N * 128;       // N x 128 halves (slabs)
    int* staging = (int*)B1;                  // 8*HB*SLICE_MAX ints, dead before B1 is written

    int nb = (N + 1023) / 1024;
    int gN = (N + 255) / 256;

    // degrees via sliced LDS histograms (no global atomics)
    hist_sliced<<<8 * HB, 256, 0, stream>>>(src, staging, E, N);
    reduce_staging<0><<<gN, 256, 0, stream>>>(staging, dsg, N);
    hist_sliced<<<8 * HB, 256, 0, stream>>>(dst, staging, E, N);
    reduce_staging<1><<<gN, 256, 0, stream>>>(staging, ddg, N);   // + exclusive prefix scanback
    norm_kernel<<<gN, 256, 0, stream>>>(dsg, ddg, ns, ndn, N);

    // row starts
    scan_partial<<<nb, 256, 0, stream>>>(ddg, bsums, N);
    scan_bsums<<<1, 128, 0, stream>>>(bsums, nb);
    scan_final<<<nb, 256, 0, stream>>>(ddg, bsums, cursor, N);

    // CSR fill: LDS cursors, plain csr stores
    fill_noatomic<<<8 * HB, 256, 0, stream>>>(src, dst, cursor, staging, csr, E, N);

    // B0 = slabbed fp16(x * ns)
    prescale_kernel<<<(N * 16 + 255) / 256, 256, 0, stream>>>(x, ns, B0, N);

    int g64 = (N + 63) / 64;
    int nrb128 = (N + 127) / 128;

    // layer 0: B1 = spmm(B0) ; B2 = relu(B1*nd @ W0 + b0)*ns
    spmm16s<<<nrb128 * 8, 256, 0, stream>>>(B0, csr, cursor, B1, N);
    gemm128h<1><<<g64, 256, 0, stream>>>(B1, ndn, ns, W0, b0, B2, N);

    // layer 1: B1 = spmm(B2) ; B0 = relu(B1*nd @ W1 + b1)*ns   (pre-scale for final agg)
    spmm16s<<<nrb128 * 8, 256, 0, stream>>>(B2, csr, cursor, B1, N);
    gemm128h<1><<<g64, 256, 0, stream>>>(B1, ndn, ns, W1, b1, B0, N);

    // layer 2: B1 = spmm(B0) (aggregate h1*ns in 128-d) ; out = (B1 @ W2)*nd + b2
    spmm16s<<<nrb128 * 8, 256, 0, stream>>>(B0, csr, cursor, B1, N);
    gemm40_final<<<(N + 31) / 32, 256, 0, stream>>>(B1, ndn, W2, b2, out, N);
}

// Round 20
// 591.242 us; speedup vs baseline: 1.4335x; 1.4335x over previous
//
#include <hip/hip_runtime.h>
#include <hip/hip_fp16.h>

#define IN_DIM 128
#define NCLS 40
#define AS_STRIDE 136   // halves; 272 B row stride
#define SLICE_MAX 12544 // max nodes per 1/8 slice (N<=100352)
#define HB 32           // edge chunks (blocks per slice)

// ---------------- sliced LDS histogram (no global atomics) ----------------

__global__ __launch_bounds__(256) void hist_sliced(const int* __restrict__ idx, int* __restrict__ staging,
                                                   int E, int N) {
    __shared__ int hist[SLICE_MAX];
    int bid = blockIdx.x;
    int slice = bid & 7;
    int b = bid >> 3;
    int chunkN = (N + 7) >> 3;
    int lo = slice * chunkN;
    int hi = min(lo + chunkN, N);
    int t = threadIdx.x;
    for (int i = t; i < SLICE_MAX; i += 256) hist[i] = 0;
    __syncthreads();
    int ce = (E + HB - 1) / HB;
    int e0 = b * ce, e1 = min(e0 + ce, E);
    int nv = (e1 - e0) >> 2;
    const int4* iv = (const int4*)(idx + e0);
    for (int k = t; k < nv; k += 256) {
        int4 d = iv[k];
        if (d.x >= lo && d.x < hi) atomicAdd(&hist[d.x - lo], 1);
        if (d.y >= lo && d.y < hi) atomicAdd(&hist[d.y - lo], 1);
        if (d.z >= lo && d.z < hi) atomicAdd(&hist[d.z - lo], 1);
        if (d.w >= lo && d.w < hi) atomicAdd(&hist[d.w - lo], 1);
    }
    for (int e = e0 + nv * 4 + t; e < e1; e += 256) {
        int d = idx[e];
        if (d >= lo && d < hi) atomicAdd(&hist[d - lo], 1);
    }
    __syncthreads();
    int* sp = staging + (size_t)(slice * HB + b) * SLICE_MAX;
    for (int i = t; i < chunkN; i += 256) sp[i] = hist[i];
}

// ---------------- reduce staging -> degree; optionally write back exclusive prefix ----------

template<int SCANBACK>
__global__ __launch_bounds__(256) void reduce_staging(int* __restrict__ staging, int* __restrict__ deg, int N) {
    int i = blockIdx.x * 256 + threadIdx.x;
    if (i >= N) return;
    int chunkN = (N + 7) >> 3;
    int slice = i / chunkN;
    int li = i - slice * chunkN;
    int* basep = staging + (size_t)slice * HB * SLICE_MAX + li;
    int acc = 0;
#pragma unroll
    for (int b = 0; b < HB; ++b) {
        int* p = basep + (size_t)b * SLICE_MAX;
        int v = *p;
        if (SCANBACK) *p = acc;
        acc += v;
    }
    deg[i] = acc;
}

__global__ __launch_bounds__(256) void norm_kernel(const int* __restrict__ ds, const int* __restrict__ dd,
                                                   float* __restrict__ ns, float* __restrict__ nd, int N) {
    int i = blockIdx.x * 256 + threadIdx.x;
    if (i < N) {
        ns[i] = ds[i] > 0 ? rsqrtf((float)ds[i]) : 0.f;
        nd[i] = dd[i] > 0 ? rsqrtf((float)dd[i]) : 0.f;
    }
}

// ---------------- exclusive scan of in-degrees -> row starts cursor[0..N] ----------------

__global__ __launch_bounds__(256) void scan_partial(const int* __restrict__ dd, int* __restrict__ bsums, int N) {
    __shared__ int sd[256];
    int t = threadIdx.x;
    int base = blockIdx.x * 1024 + t * 4;
    int s = 0;
#pragma unroll
    for (int k = 0; k < 4; ++k) { int i = base + k; if (i < N) s += dd[i]; }
    sd[t] = s;
    __syncthreads();
    for (int off = 128; off > 0; off >>= 1) {
        if (t < off) sd[t] += sd[t + off];
        __syncthreads();
    }
    if (t == 0) bsums[blockIdx.x] = sd[0];
}

__global__ __launch_bounds__(128) void scan_bsums(int* __restrict__ bsums, int nb) {
    __shared__ int sd[128];
    __shared__ int carry_s;
    int t = threadIdx.x;
    if (t == 0) carry_s = 0;
    __syncthreads();
    for (int base = 0; base < nb; base += 128) {
        int i = base + t;
        int orig = (i < nb) ? bsums[i] : 0;
        sd[t] = orig;
        __syncthreads();
        for (int off = 1; off < 128; off <<= 1) {
            int u = (t >= off) ? sd[t - off] : 0;
            __syncthreads();
            sd[t] += u;
            __syncthreads();
        }
        int carry = carry_s;
        if (i < nb) bsums[i] = carry + sd[t] - orig;   // exclusive
        __syncthreads();
        if (t == 127) carry_s = carry + sd[127];
        __syncthreads();
    }
}

__global__ __launch_bounds__(256) void scan_final(const int* __restrict__ dd, const int* __restrict__ bsums,
                                                  int* __restrict__ cursor, int N) {
    __shared__ int sd[256];
    int t = threadIdx.x;
    int base = blockIdx.x * 1024 + t * 4;
    int v[4]; int s = 0;
#pragma unroll
    for (int k = 0; k < 4; ++k) { int i = base + k; v[k] = (i < N) ? dd[i] : 0; s += v[k]; }
    sd[t] = s;
    __syncthreads();
    for (int off = 1; off < 256; off <<= 1) {
        int u = (t >= off) ? sd[t - off] : 0;
        __syncthreads();
        sd[t] += u;
        __syncthreads();
    }
    int excl = sd[t] - s + bsums[blockIdx.x];
#pragma unroll
    for (int k = 0; k < 4; ++k) {
        int i = base + k;
        if (i < N) {
            cursor[i] = excl;       // exclusive row start
            excl += v[k];
            if (i == N - 1) cursor[N] = excl;
        }
    }
}

// ---------------- CSR fill: LDS cursors (rowstart + staged prefix), no global atomics -------

__global__ __launch_bounds__(256) void fill_noatomic(const int* __restrict__ src, const int* __restrict__ dst,
                                                     const int* __restrict__ rowstart, const int* __restrict__ staging,
                                                     int* __restrict__ csr, int E, int N) {
    __shared__ int cur[SLICE_MAX];
    int bid = blockIdx.x;
    int slice = bid & 7;
    int b = bid >> 3;
    int chunkN = (N + 7) >> 3;
    int lo = slice * chunkN;
    int hi = min(lo + chunkN, N);
    int t = threadIdx.x;
    const int* sp = staging + (size_t)(slice * HB + b) * SLICE_MAX;
    for (int i = t; i < chunkN; i += 256) cur[i] = rowstart[lo + i] + sp[i];
    __syncthreads();
    int ce = (E + HB - 1) / HB;
    int e0 = b * ce, e1 = min(e0 + ce, E);
    int nv = (e1 - e0) >> 2;
    const int4* dv4 = (const int4*)(dst + e0);
    const int4* sv4 = (const int4*)(src + e0);
    for (int k = t; k < nv; k += 256) {
        int4 d = dv4[k];
        int4 sv = sv4[k];
        if (d.x >= lo && d.x < hi) csr[atomicAdd(&cur[d.x - lo], 1)] = sv.x;
        if (d.y >= lo && d.y < hi) csr[atomicAdd(&cur[d.y - lo], 1)] = sv.y;
        if (d.z >= lo && d.z < hi) csr[atomicAdd(&cur[d.z - lo], 1)] = sv.z;
        if (d.w >= lo && d.w < hi) csr[atomicAdd(&cur[d.w - lo], 1)] = sv.w;
    }
    for (int e = e0 + nv * 4 + t; e < e1; e += 256) {
        int d = dst[e];
        if (d >= lo && d < hi) csr[atomicAdd(&cur[d - lo], 1)] = src[e];
    }
}

// ---------------- helpers ----------------

__device__ __forceinline__ float4 zero4() { return make_float4(0.f, 0.f, 0.f, 0.f); }

__device__ __forceinline__ void fma4(float4& acc, float s, const float4& wv) {
    acc.x = fmaf(s, wv.x, acc.x);
    acc.y = fmaf(s, wv.y, acc.y);
    acc.z = fmaf(s, wv.z, acc.z);
    acc.w = fmaf(s, wv.w, acc.w);
}

__device__ __forceinline__ void add_h8(float4& a0, float4& a1, const int4& v) {
    const __half2* h = (const __half2*)&v;
    float2 f0 = __half22float2(h[0]);
    float2 f1 = __half22float2(h[1]);
    float2 f2 = __half22float2(h[2]);
    float2 f3 = __half22float2(h[3]);
    a0.x += f0.x; a0.y += f0.y; a0.z += f1.x; a0.w += f1.y;
    a1.x += f2.x; a1.y += f2.y; a1.z += f3.x; a1.w += f3.y;
}

__device__ __forceinline__ int4 pack_h8(const float4& o0, const float4& o1) {
    int4 p;
    __half2* ph = (__half2*)&p;
    ph[0] = __float22half2_rn(make_float2(o0.x, o0.y));
    ph[1] = __float22half2_rn(make_float2(o0.z, o0.w));
    ph[2] = __float22half2_rn(make_float2(o1.x, o1.y));
    ph[3] = __float22half2_rn(make_float2(o1.z, o1.w));
    return p;
}

// ---------------- prescale into slabs: slab s holds halves [16s,16s+16) of every row ----------

__global__ __launch_bounds__(256) void prescale_kernel(const float* __restrict__ x, const float* __restrict__ ns,
                                                       __half* __restrict__ xs, int N) {
    int tid = blockIdx.x * 256 + threadIdx.x;     // over 16N int4s, slab-major
    if (tid >= N * 16) return;
    int s = tid / (2 * N);
    int rem = tid - s * 2 * N;
    int n = rem >> 1;
    int h = rem & 1;
    float sc = ns[n];
    const float4* xp = (const float4*)x + (size_t)n * 32 + (s * 2 + h) * 2;
    float4 v0 = xp[0], v1 = xp[1];
    v0.x *= sc; v0.y *= sc; v0.z *= sc; v0.w *= sc;
    v1.x *= sc; v1.y *= sc; v1.z *= sc; v1.w *= sc;
    ((int4*)xs)[tid] = pack_h8(v0, v1);
}

// ---------------- slab SpMM: agg_slab[s][r] = sum_{src in N(r)} x_slab[s][src] ----------------
// grid = nrb*8; slice = bid&7 (XCD-pinned 3.2 MB slab). 2 wave-adjacent threads/row.

__global__ __launch_bounds__(256) void spmm16s(const __half* __restrict__ xs, const int* __restrict__ csr,
                                               const int* __restrict__ cursor, __half* __restrict__ as_, int N) {
    int bid = blockIdx.x;
    int slice = bid & 7;
    int rb = bid >> 3;
    int r = rb * 128 + (threadIdx.x >> 1);
    if (r >= N) return;
    int h = threadIdx.x & 1;
    const int4* xi = (const int4*)xs + (size_t)slice * N * 2;
    int start = cursor[r];
    int end = cursor[r + 1];
    float4 a0 = zero4(), a1 = zero4();
    int e = start;
    for (; e + 4 <= end; e += 4) {
        int i0 = csr[e + 0], i1 = csr[e + 1], i2 = csr[e + 2], i3 = csr[e + 3];
        int4 v0 = xi[(size_t)i0 * 2 + h];
        int4 v1 = xi[(size_t)i1 * 2 + h];
        int4 v2 = xi[(size_t)i2 * 2 + h];
        int4 v3 = xi[(size_t)i3 * 2 + h];
        add_h8(a0, a1, v0); add_h8(a0, a1, v1);
        add_h8(a0, a1, v2); add_h8(a0, a1, v3);
    }
    for (; e < end; ++e) {
        int4 v0 = xi[(size_t)csr[e] * 2 + h];
        add_h8(a0, a1, v0);
    }
    ((int4*)as_)[(size_t)slice * N * 2 + (size_t)r * 2 + h] = pack_h8(a0, a1);
}

// ---------------- GEMM 128(fp16 slab agg) -> 128, epilogue acc*nd+bias, relu, (*ns) -> slabs --

template<int SCALE_NS>
__global__ __launch_bounds__(256, 6) void gemm128h(const __half* __restrict__ agg, const float* __restrict__ nd,
                                                   const float* __restrict__ ns, const float* __restrict__ W,
                                                   const float* __restrict__ bias, __half* __restrict__ out, int N) {
    __shared__ __half As[64 * AS_STRIDE];
    int t = threadIdx.x;
    int row0 = blockIdx.x * 64;

#pragma unroll
    for (int i = 0; i < 4; ++i) {
        int idx = t + 256 * i;          // 0..1023
        int s = idx >> 7;
        int rem = idx & 127;
        int r = rem >> 1;
        int h = rem & 1;
        int gr = row0 + r;
        int4 v = make_int4(0, 0, 0, 0);
        if (gr < N) v = ((const int4*)agg)[(size_t)s * N * 2 + (size_t)gr * 2 + h];
        *(int4*)&As[r * AS_STRIDE + (s * 2 + h) * 8] = v;
    }
    __syncthreads();

    int rg = t >> 4;
    int cgp = t & 15;
    int rbase = rg * 4;
    const float4* Wg = (const float4*)W;
    float4 acc[4][2];
#pragma unroll
    for (int m = 0; m < 4; ++m) { acc[m][0] = zero4(); acc[m][1] = zero4(); }
#pragma unroll 2
    for (int k4 = 0; k4 < 32; ++k4) {
        int k0 = k4 * 4;
        float4 a[4];
#pragma unroll
        for (int m = 0; m < 4; ++m) {
            uint2 raw = *(const uint2*)&As[(rbase + m) * AS_STRIDE + k0];
            const __half2* hp = (const __half2*)&raw;
            float2 f0 = __half22float2(hp[0]);
            float2 f1 = __half22float2(hp[1]);
            a[m] = make_float4(f0.x, f0.y, f1.x, f1.y);
        }
        float4 w[4][2];
#pragma unroll
        for (int j = 0; j < 4; ++j) {
            w[j][0] = Wg[(k0 + j) * 32 + cgp * 2 + 0];
            w[j][1] = Wg[(k0 + j) * 32 + cgp * 2 + 1];
        }
#pragma unroll
        for (int m = 0; m < 4; ++m) {
            fma4(acc[m][0], a[m].x, w[0][0]); fma4(acc[m][1], a[m].x, w[0][1]);
            fma4(acc[m][0], a[m].y, w[1][0]); fma4(acc[m][1], a[m].y, w[1][1]);
            fma4(acc[m][0], a[m].z, w[2][0]); fma4(acc[m][1], a[m].z, w[2][1]);
            fma4(acc[m][0], a[m].w, w[3][0]); fma4(acc[m][1], a[m].w, w[3][1]);
        }
    }

    float4 bb0 = ((const float4*)bias)[cgp * 2 + 0];
    float4 bb1 = ((const float4*)bias)[cgp * 2 + 1];
    int os = cgp >> 1, oh = cgp & 1;
#pragma unroll
    for (int m = 0; m < 4; ++m) {
        int gr = row0 + rbase + m;
        if (gr < N) {
            float ndr = nd[gr];
            float4 o0, o1;
            o0.x = fmaxf(fmaf(acc[m][0].x, ndr, bb0.x), 0.f);
            o0.y = fmaxf(fmaf(acc[m][0].y, ndr, bb0.y), 0.f);
            o0.z = fmaxf(fmaf(acc[m][0].z, ndr, bb0.z), 0.f);
            o0.w = fmaxf(fmaf(acc[m][0].w, ndr, bb0.w), 0.f);
            o1.x = fmaxf(fmaf(acc[m][1].x, ndr, bb1.x), 0.f);
            o1.y = fmaxf(fmaf(acc[m][1].y, ndr, bb1.y), 0.f);
            o1.z = fmaxf(fmaf(acc[m][1].z, ndr, bb1.z), 0.f);
            o1.w = fmaxf(fmaf(acc[m][1].w, ndr, bb1.w), 0.f);
            if (SCALE_NS) {
                float s = ns[gr];
                o0.x *= s; o0.y *= s; o0.z *= s; o0.w *= s;
                o1.x *= s; o1.y *= s; o1.z *= s; o1.w *= s;
            }
            ((int4*)out)[(size_t)os * N * 2 + (size_t)gr * 2 + oh] = pack_h8(o0, o1);
        }
    }
}

// ---------------- GEMM 128(slab fp16) -> 40, *ns, output 5 slabs of int4 (8 halves) ----------

__global__ __launch_bounds__(256) void gemm40_kernel(const __half* __restrict__ A, const float* __restrict__ W,
                                                     const float* __restrict__ ns, __half* __restrict__ y, int N) {
    __shared__ float Ws[128 * NCLS];   // 20 KB
    __shared__ float As[32 * 132];     // 16.5 KB
    __shared__ __half ys[32][40];      // 2.5 KB
    int t = threadIdx.x;
    int row0 = blockIdx.x * 32;

#pragma unroll
    for (int i = 0; i < 5; ++i) {
        int idx = t + 256 * i;
        ((float4*)Ws)[idx] = ((const float4*)W)[idx];
    }
#pragma unroll
    for (int i = 0; i < 2; ++i) {
        int idx = t + 256 * i;        // 0..511
        int s = idx >> 6;
        int rem = idx & 63;
        int r = rem >> 1;
        int h = rem & 1;
        int gr = row0 + r;
        int4 v = make_int4(0, 0, 0, 0);
        if (gr < N) v = ((const int4*)A)[(size_t)s * N * 2 + (size_t)gr * 2 + h];
        const __half2* hh = (const __half2*)&v;
        float2 f0 = __half22float2(hh[0]);
        float2 f1 = __half22float2(hh[1]);
        float2 f2 = __half22float2(hh[2]);
        float2 f3 = __half22float2(hh[3]);
        float* dp = &As[r * 132 + (s * 2 + h) * 8];
        dp[0] = f0.x; dp[1] = f0.y; dp[2] = f1.x; dp[3] = f1.y;
        dp[4] = f2.x; dp[5] = f2.y; dp[6] = f3.x; dp[7] = f3.y;
    }
    __syncthreads();

    int row = t >> 3;
    int cg = t & 7;
    float acc[5] = {0.f, 0.f, 0.f, 0.f, 0.f};
#pragma unroll 2
    for (int k4 = 0; k4 < 32; ++k4) {
        float4 a = *(const float4*)&As[row * 132 + k4 * 4];
#pragma unroll
        for (int j = 0; j < 4; ++j) {
            float av = (j == 0) ? a.x : (j == 1) ? a.y : (j == 2) ? a.z : a.w;
            const float* wp = &Ws[(k4 * 4 + j) * NCLS + cg * 5];
            acc[0] = fmaf(av, wp[0], acc[0]);
            acc[1] = fmaf(av, wp[1], acc[1]);
            acc[2] = fmaf(av, wp[2], acc[2]);
            acc[3] = fmaf(av, wp[3], acc[3]);
            acc[4] = fmaf(av, wp[4], acc[4]);
        }
    }
    {
        int gr = row0 + row;
        float s = (gr < N) ? ns[gr] : 0.f;
        __half* yp = &ys[row][cg * 5];
        yp[0] = __float2half_rn(acc[0] * s);
        yp[1] = __float2half_rn(acc[1] * s);
        yp[2] = __float2half_rn(acc[2] * s);
        yp[3] = __float2half_rn(acc[3] * s);
        yp[4] = __float2half_rn(acc[4] * s);
    }
    __syncthreads();
    if (t < 160) {
        int s = t >> 5;      // 0..4
        int r = t & 31;
        int gr = row0 + r;
        if (gr < N) ((int4*)y)[(size_t)s * N + gr] = *(const int4*)&ys[r][s * 8];
    }
}

// ---------------- slab gather 40-d + *nd + b2 -> out (fp32) ----------------
// grid = nrb256*8; slice = bid&7 (XCD-pinned; slices 5-7 idle). Slab = 1.6 MB, L2-resident.

__global__ __launch_bounds__(256) void gather40f(const __half* __restrict__ y, const int* __restrict__ csr,
                                                 const int* __restrict__ cursor, const float* __restrict__ nd,
                                                 const float* __restrict__ b2, float* __restrict__ out, int N) {
    int bid = blockIdx.x;
    int slice = bid & 7;
    if (slice >= 5) return;
    int rb = bid >> 3;
    int r = rb * 256 + threadIdx.x;
    if (r >= N) return;
    const int4* ys = (const int4*)y + (size_t)slice * N;
    int start = cursor[r];
    int end = cursor[r + 1];
    float4 a0 = zero4(), a1 = zero4();
    int e = start;
    for (; e + 4 <= end; e += 4) {
        int i0 = csr[e + 0], i1 = csr[e + 1], i2 = csr[e + 2], i3 = csr[e + 3];
        int4 v0 = ys[i0];
        int4 v1 = ys[i1];
        int4 v2 = ys[i2];
        int4 v3 = ys[i3];
        add_h8(a0, a1, v0); add_h8(a0, a1, v1);
        add_h8(a0, a1, v2); add_h8(a0, a1, v3);
    }
    for (; e < end; ++e) {
        int4 v0 = ys[csr[e]];
        add_h8(a0, a1, v0);
    }
    float s = nd[r];
    const float* bp = b2 + slice * 8;
    float4 o0, o1;
    o0.x = fmaf(a0.x, s, bp[0]); o0.y = fmaf(a0.y, s, bp[1]);
    o0.z = fmaf(a0.z, s, bp[2]); o0.w = fmaf(a0.w, s, bp[3]);
    o1.x = fmaf(a1.x, s, bp[4]); o1.y = fmaf(a1.y, s, bp[5]);
    o1.z = fmaf(a1.z, s, bp[6]); o1.w = fmaf(a1.w, s, bp[7]);
    float* op = out + (size_t)r * NCLS + slice * 8;
    *(float4*)(op + 0) = o0;
    *(float4*)(op + 4) = o1;
}

extern "C" void kernel_launch(void* const* d_in, const int* in_sizes, int n_in,
                              void* d_out, int out_size, void* d_ws, size_t ws_size,
                              hipStream_t stream) {
    const float* x  = (const float*)d_in[0];
    const int* src  = (const int*)d_in[1];
    const int* dst  = (const int*)d_in[2];
    const float* W0 = (const float*)d_in[3];
    const float* b0 = (const float*)d_in[4];
    const float* W1 = (const float*)d_in[5];
    const float* b1 = (const float*)d_in[6];
    const float* W2 = (const float*)d_in[7];
    const float* b2 = (const float*)d_in[8];
    float* out = (float*)d_out;

    int N = in_sizes[0] / IN_DIM;
    int E = in_sizes[1];

    float* base = (float*)d_ws;
    float* ns   = base;                       // N
    float* ndn  = base + (size_t)N;           // N
    int* dsg    = (int*)(base + 2 * (size_t)N);
    int* ddg    = dsg + (size_t)N;
    int* cursor = ddg + (size_t)N;            // N+1
    int* bsums  = cursor + (size_t)N + 1;     // 1024
    int* csr    = bsums + 1024;               // E
    __half* B0  = (__half*)(csr + (size_t)E); // N x 128 halves (slabs)
    __half* B1  = B0 + (size_t)N * 128;       // N x 128 halves (slabs)
    __half* B2  = B1 + (size_t)N * 128;       // N x 128 halves (slabs)
    __half* yh  = B2 + (size_t)N * 128;       // 5 slabs x N int4
    int* staging = (int*)B1;                  // 8*HB*SLICE_MAX ints, dead before B1 is written

    int nb = (N + 1023) / 1024;
    int gN = (N + 255) / 256;

    // degrees via sliced LDS histograms (no global atomics)
    hist_sliced<<<8 * HB, 256, 0, stream>>>(src, staging, E, N);
    reduce_staging<0><<<gN, 256, 0, stream>>>(staging, dsg, N);
    hist_sliced<<<8 * HB, 256, 0, stream>>>(dst, staging, E, N);
    reduce_staging<1><<<gN, 256, 0, stream>>>(staging, ddg, N);   // + exclusive prefix scanback
    norm_kernel<<<gN, 256, 0, stream>>>(dsg, ddg, ns, ndn, N);

    // row starts
    scan_partial<<<nb, 256, 0, stream>>>(ddg, bsums, N);
    scan_bsums<<<1, 128, 0, stream>>>(bsums, nb);
    scan_final<<<nb, 256, 0, stream>>>(ddg, bsums, cursor, N);

    // CSR fill: LDS cursors, plain csr stores
    fill_noatomic<<<8 * HB, 256, 0, stream>>>(src, dst, cursor, staging, csr, E, N);

    // B0 = slabbed fp16(x * ns)
    prescale_kernel<<<(N * 16 + 255) / 256, 256, 0, stream>>>(x, ns, B0, N);

    int g64 = (N + 63) / 64;
    int nrb128 = (N + 127) / 128;
    int nrb256 = (N + 255) / 256;

    // layer 0: B1 = spmm(B0) ; B2 = relu(B1*nd @ W0 + b0)*ns   (all slabbed)
    spmm16s<<<nrb128 * 8, 256, 0, stream>>>(B0, csr, cursor, B1, N);
    gemm128h<1><<<g64, 256, 0, stream>>>(B1, ndn, ns, W0, b0, B2, N);

    // layer 1: B1 = spmm(B2) ; B0 = relu(B1*nd @ W1 + b1)
    spmm16s<<<nrb128 * 8, 256, 0, stream>>>(B2, csr, cursor, B1, N);
    gemm128h<0><<<g64, 256, 0, stream>>>(B1, ndn, ns, W1, b1, B0, N);

    // layer 2: yh = (B0 @ W2)*ns (5 slabs) ; out = gather40(yh)*nd + b2
    gemm40_kernel<<<(N + 31) / 32, 256, 0, stream>>>(B0, W2, ns, yh, N);
    gather40f<<<nrb256 * 8, 256, 0, stream>>>(yh, csr, cursor, ndn, b2, out, N);
}

// Round 21
// 570.172 us; speedup vs baseline: 1.4865x; 1.0370x over previous
//
#include <hip/hip_runtime.h>
#include <hip/hip_fp16.h>

#define IN_DIM 128
#define NCLS 40
#define AS_STRIDE 136   // halves; 272 B row stride
#define SLICE_MAX 12544 // max nodes per 1/8 slice (N<=100352)
#define HB 32           // edge chunks (blocks per slice)
#define ECHUNK 4096     // staged csr entries (16 KB LDS)

typedef int ivec4 __attribute__((ext_vector_type(4)));

__device__ __forceinline__ int ntl_i(const int* p) { return __builtin_nontemporal_load(p); }

// ---------------- sliced LDS histogram (no global atomics) ----------------

__global__ __launch_bounds__(256) void hist_sliced(const int* __restrict__ idx, int* __restrict__ staging,
                                                   int E, int N) {
    __shared__ int hist[SLICE_MAX];
    int bid = blockIdx.x;
    int slice = bid & 7;
    int b = bid >> 3;
    int chunkN = (N + 7) >> 3;
    int lo = slice * chunkN;
    int hi = min(lo + chunkN, N);
    int t = threadIdx.x;
    for (int i = t; i < SLICE_MAX; i += 256) hist[i] = 0;
    __syncthreads();
    int ce = (E + HB - 1) / HB;
    int e0 = b * ce, e1 = min(e0 + ce, E);
    int nv = (e1 - e0) >> 2;
    const int4* iv = (const int4*)(idx + e0);
    for (int k = t; k < nv; k += 256) {
        int4 d = iv[k];
        if (d.x >= lo && d.x < hi) atomicAdd(&hist[d.x - lo], 1);
        if (d.y >= lo && d.y < hi) atomicAdd(&hist[d.y - lo], 1);
        if (d.z >= lo && d.z < hi) atomicAdd(&hist[d.z - lo], 1);
        if (d.w >= lo && d.w < hi) atomicAdd(&hist[d.w - lo], 1);
    }
    for (int e = e0 + nv * 4 + t; e < e1; e += 256) {
        int d = idx[e];
        if (d >= lo && d < hi) atomicAdd(&hist[d - lo], 1);
    }
    __syncthreads();
    int* sp = staging + (size_t)(slice * HB + b) * SLICE_MAX;
    for (int i = t; i < chunkN; i += 256) sp[i] = hist[i];
}

// ---------------- reduce staging -> degree; optionally write back exclusive prefix ----------

template<int SCANBACK>
__global__ __launch_bounds__(256) void reduce_staging(int* __restrict__ staging, int* __restrict__ deg, int N) {
    int i = blockIdx.x * 256 + threadIdx.x;
    if (i >= N) return;
    int chunkN = (N + 7) >> 3;
    int slice = i / chunkN;
    int li = i - slice * chunkN;
    int* basep = staging + (size_t)slice * HB * SLICE_MAX + li;
    int acc = 0;
#pragma unroll
    for (int b = 0; b < HB; ++b) {
        int* p = basep + (size_t)b * SLICE_MAX;
        int v = *p;
        if (SCANBACK) *p = acc;
        acc += v;
    }
    deg[i] = acc;
}

__global__ __launch_bounds__(256) void norm_kernel(const int* __restrict__ ds, const int* __restrict__ dd,
                                                   float* __restrict__ ns, float* __restrict__ nd, int N) {
    int i = blockIdx.x * 256 + threadIdx.x;
    if (i < N) {
        ns[i] = ds[i] > 0 ? rsqrtf((float)ds[i]) : 0.f;
        nd[i] = dd[i] > 0 ? rsqrtf((float)dd[i]) : 0.f;
    }
}

// ---------------- exclusive scan of in-degrees -> row starts cursor[0..N] ----------------

__global__ __launch_bounds__(256) void scan_partial(const int* __restrict__ dd, int* __restrict__ bsums, int N) {
    __shared__ int sd[256];
    int t = threadIdx.x;
    int base = blockIdx.x * 1024 + t * 4;
    int s = 0;
#pragma unroll
    for (int k = 0; k < 4; ++k) { int i = base + k; if (i < N) s += dd[i]; }
    sd[t] = s;
    __syncthreads();
    for (int off = 128; off > 0; off >>= 1) {
        if (t < off) sd[t] += sd[t + off];
        __syncthreads();
    }
    if (t == 0) bsums[blockIdx.x] = sd[0];
}

__global__ __launch_bounds__(128) void scan_bsums(int* __restrict__ bsums, int nb) {
    __shared__ int sd[128];
    __shared__ int carry_s;
    int t = threadIdx.x;
    if (t == 0) carry_s = 0;
    __syncthreads();
    for (int base = 0; base < nb; base += 128) {
        int i = base + t;
        int orig = (i < nb) ? bsums[i] : 0;
        sd[t] = orig;
        __syncthreads();
        for (int off = 1; off < 128; off <<= 1) {
            int u = (t >= off) ? sd[t - off] : 0;
            __syncthreads();
            sd[t] += u;
            __syncthreads();
        }
        int carry = carry_s;
        if (i < nb) bsums[i] = carry + sd[t] - orig;   // exclusive
        __syncthreads();
        if (t == 127) carry_s = carry + sd[127];
        __syncthreads();
    }
}

__global__ __launch_bounds__(256) void scan_final(const int* __restrict__ dd, const int* __restrict__ bsums,
                                                  int* __restrict__ cursor, int N) {
    __shared__ int sd[256];
    int t = threadIdx.x;
    int base = blockIdx.x * 1024 + t * 4;
    int v[4]; int s = 0;
#pragma unroll
    for (int k = 0; k < 4; ++k) { int i = base + k; v[k] = (i < N) ? dd[i] : 0; s += v[k]; }
    sd[t] = s;
    __syncthreads();
    for (int off = 1; off < 256; off <<= 1) {
        int u = (t >= off) ? sd[t - off] : 0;
        __syncthreads();
        sd[t] += u;
        __syncthreads();
    }
    int excl = sd[t] - s + bsums[blockIdx.x];
#pragma unroll
    for (int k = 0; k < 4; ++k) {
        int i = base + k;
        if (i < N) {
            cursor[i] = excl;       // exclusive row start
            excl += v[k];
            if (i == N - 1) cursor[N] = excl;
        }
    }
}

// ---------------- CSR fill: LDS cursors (rowstart + staged prefix), no global atomics -------

__global__ __launch_bounds__(256) void fill_noatomic(const int* __restrict__ src, const int* __restrict__ dst,
                                                     const int* __restrict__ rowstart, const int* __restrict__ staging,
                                                     int* __restrict__ csr, int E, int N) {
    __shared__ int cur[SLICE_MAX];
    int bid = blockIdx.x;
    int slice = bid & 7;
    int b = bid >> 3;
    int chunkN = (N + 7) >> 3;
    int lo = slice * chunkN;
    int hi = min(lo + chunkN, N);
    int t = threadIdx.x;
    const int* sp = staging + (size_t)(slice * HB + b) * SLICE_MAX;
    for (int i = t; i < chunkN; i += 256) cur[i] = rowstart[lo + i] + sp[i];
    __syncthreads();
    int ce = (E + HB - 1) / HB;
    int e0 = b * ce, e1 = min(e0 + ce, E);
    int nv = (e1 - e0) >> 2;
    const int4* dv4 = (const int4*)(dst + e0);
    const int4* sv4 = (const int4*)(src + e0);
    for (int k = t; k < nv; k += 256) {
        int4 d = dv4[k];
        int4 sv = sv4[k];
        if (d.x >= lo && d.x < hi) csr[atomicAdd(&cur[d.x - lo], 1)] = sv.x;
        if (d.y >= lo && d.y < hi) csr[atomicAdd(&cur[d.y - lo], 1)] = sv.y;
        if (d.z >= lo && d.z < hi) csr[atomicAdd(&cur[d.z - lo], 1)] = sv.z;
        if (d.w >= lo && d.w < hi) csr[atomicAdd(&cur[d.w - lo], 1)] = sv.w;
    }
    for (int e = e0 + nv * 4 + t; e < e1; e += 256) {
        int d = dst[e];
        if (d >= lo && d < hi) csr[atomicAdd(&cur[d - lo], 1)] = src[e];
    }
}

// ---------------- helpers ----------------

__device__ __forceinline__ float4 zero4() { return make_float4(0.f, 0.f, 0.f, 0.f); }

__device__ __forceinline__ void fma4(float4& acc, float s, const float4& wv) {
    acc.x = fmaf(s, wv.x, acc.x);
    acc.y = fmaf(s, wv.y, acc.y);
    acc.z = fmaf(s, wv.z, acc.z);
    acc.w = fmaf(s, wv.w, acc.w);
}

__device__ __forceinline__ void add_h8(float4& a0, float4& a1, const int4& v) {
    const __half2* h = (const __half2*)&v;
    float2 f0 = __half22float2(h[0]);
    float2 f1 = __half22float2(h[1]);
    float2 f2 = __half22float2(h[2]);
    float2 f3 = __half22float2(h[3]);
    a0.x += f0.x; a0.y += f0.y; a0.z += f1.x; a0.w += f1.y;
    a1.x += f2.x; a1.y += f2.y; a1.z += f3.x; a1.w += f3.y;
}

__device__ __forceinline__ int4 pack_h8(const float4& o0, const float4& o1) {
    int4 p;
    __half2* ph = (__half2*)&p;
    ph[0] = __float22half2_rn(make_float2(o0.x, o0.y));
    ph[1] = __float22half2_rn(make_float2(o0.z, o0.w));
    ph[2] = __float22half2_rn(make_float2(o1.x, o1.y));
    ph[3] = __float22half2_rn(make_float2(o1.z, o1.w));
    return p;
}

// ---------------- prescale into slabs: slab s holds halves [16s,16s+16) of every row ----------

__global__ __launch_bounds__(256) void prescale_kernel(const float* __restrict__ x, const float* __restrict__ ns,
                                                       __half* __restrict__ xs, int N) {
    int tid = blockIdx.x * 256 + threadIdx.x;     // over 16N int4s, slab-major
    if (tid >= N * 16) return;
    int s = tid / (2 * N);
    int rem = tid - s * 2 * N;
    int n = rem >> 1;
    int h = rem & 1;
    float sc = ns[n];
    const float4* xp = (const float4*)x + (size_t)n * 32 + (s * 2 + h) * 2;
    float4 v0 = xp[0], v1 = xp[1];
    v0.x *= sc; v0.y *= sc; v0.z *= sc; v0.w *= sc;
    v1.x *= sc; v1.y *= sc; v1.z *= sc; v1.w *= sc;
    ((int4*)xs)[tid] = pack_h8(v0, v1);
}

// ---------------- slab SpMM: 2 wave-adjacent threads/row, LDS-staged csr ----------------
// grid = ceil(N/128)*8; slice = bid&7 (XCD-pinned 3.2 MB slab). Block's rows own a
// contiguous csr span: staged in 16 KB LDS chunks (coalesced NT reads, read-once),
// slab gather loads coalesce across the lane pair.

__global__ __launch_bounds__(256) void spmm16s(const __half* __restrict__ xs, const int* __restrict__ csr,
                                               const int* __restrict__ cursor, __half* __restrict__ as_, int N) {
    __shared__ int eidx[ECHUNK];
    int bid = blockIdx.x;
    int slice = bid & 7;
    int rb = bid >> 3;
    int row0 = rb * 128;
    int t = threadIdx.x;
    int r = row0 + (t >> 1);
    int h = t & 1;
    const int4* xi = (const int4*)xs + (size_t)slice * N * 2;
    int start = 0, end = 0;
    if (r < N) { start = cursor[r]; end = cursor[r + 1]; }
    int rend = min(row0 + 128, N);
    int estart = cursor[row0];
    int eend = cursor[rend];
    float4 a0 = zero4(), a1 = zero4();
    for (int cb = estart; cb < eend; cb += ECHUNK) {
        int cn = min(ECHUNK, eend - cb);
        for (int i = t; i < cn; i += 256) eidx[i] = ntl_i(csr + cb + i);
        __syncthreads();
        int lo = max(start, cb);
        int hi2 = min(end, cb + cn);
        int e = lo;
        for (; e + 4 <= hi2; e += 4) {
            int i0 = eidx[e - cb + 0];
            int i1 = eidx[e - cb + 1];
            int i2 = eidx[e - cb + 2];
            int i3 = eidx[e - cb + 3];
            int4 v0 = xi[(size_t)i0 * 2 + h];
            int4 v1 = xi[(size_t)i1 * 2 + h];
            int4 v2 = xi[(size_t)i2 * 2 + h];
            int4 v3 = xi[(size_t)i3 * 2 + h];
            add_h8(a0, a1, v0); add_h8(a0, a1, v1);
            add_h8(a0, a1, v2); add_h8(a0, a1, v3);
        }
        for (; e < hi2; ++e) {
            int4 v = xi[(size_t)eidx[e - cb] * 2 + h];
            add_h8(a0, a1, v);
        }
        __syncthreads();
    }
    if (r < N) {
        ((int4*)as_)[(size_t)slice * N * 2 + (size_t)r * 2 + h] = pack_h8(a0, a1);
    }
}

// ---------------- GEMM 128(fp16 slab agg) -> 128, epilogue acc*nd+bias, relu, (*ns) -> slabs --

template<int SCALE_NS>
__global__ __launch_bounds__(256, 6) void gemm128h(const __half* __restrict__ agg, const float* __restrict__ nd,
                                                   const float* __restrict__ ns, const float* __restrict__ W,
                                                   const float* __restrict__ bias, __half* __restrict__ out, int N) {
    __shared__ __half As[64 * AS_STRIDE];
    int t = threadIdx.x;
    int row0 = blockIdx.x * 64;

#pragma unroll
    for (int i = 0; i < 4; ++i) {
        int idx = t + 256 * i;          // 0..1023
        int s = idx >> 7;
        int rem = idx & 127;
        int r = rem >> 1;
        int h = rem & 1;
        int gr = row0 + r;
        int4 v = make_int4(0, 0, 0, 0);
        if (gr < N) v = ((const int4*)agg)[(size_t)s * N * 2 + (size_t)gr * 2 + h];
        *(int4*)&As[r * AS_STRIDE + (s * 2 + h) * 8] = v;
    }
    __syncthreads();

    int rg = t >> 4;
    int cgp = t & 15;
    int rbase = rg * 4;
    const float4* Wg = (const float4*)W;
    float4 acc[4][2];
#pragma unroll
    for (int m = 0; m < 4; ++m) { acc[m][0] = zero4(); acc[m][1] = zero4(); }
#pragma unroll 2
    for (int k4 = 0; k4 < 32; ++k4) {
        int k0 = k4 * 4;
        float4 a[4];
#pragma unroll
        for (int m = 0; m < 4; ++m) {
            uint2 raw = *(const uint2*)&As[(rbase + m) * AS_STRIDE + k0];
            const __half2* hp = (const __half2*)&raw;
            float2 f0 = __half22float2(hp[0]);
            float2 f1 = __half22float2(hp[1]);
            a[m] = make_float4(f0.x, f0.y, f1.x, f1.y);
        }
        float4 w[4][2];
#pragma unroll
        for (int j = 0; j < 4; ++j) {
            w[j][0] = Wg[(k0 + j) * 32 + cgp * 2 + 0];
            w[j][1] = Wg[(k0 + j) * 32 + cgp * 2 + 1];
        }
#pragma unroll
        for (int m = 0; m < 4; ++m) {
            fma4(acc[m][0], a[m].x, w[0][0]); fma4(acc[m][1], a[m].x, w[0][1]);
            fma4(acc[m][0], a[m].y, w[1][0]); fma4(acc[m][1], a[m].y, w[1][1]);
            fma4(acc[m][0], a[m].z, w[2][0]); fma4(acc[m][1], a[m].z, w[2][1]);
            fma4(acc[m][0], a[m].w, w[3][0]); fma4(acc[m][1], a[m].w, w[3][1]);
        }
    }

    float4 bb0 = ((const float4*)bias)[cgp * 2 + 0];
    float4 bb1 = ((const float4*)bias)[cgp * 2 + 1];
    int os = cgp >> 1, oh = cgp & 1;
#pragma unroll
    for (int m = 0; m < 4; ++m) {
        int gr = row0 + rbase + m;
        if (gr < N) {
            float ndr = nd[gr];
            float4 o0, o1;
            o0.x = fmaxf(fmaf(acc[m][0].x, ndr, bb0.x), 0.f);
            o0.y = fmaxf(fmaf(acc[m][0].y, ndr, bb0.y), 0.f);
            o0.z = fmaxf(fmaf(acc[m][0].z, ndr, bb0.z), 0.f);
            o0.w = fmaxf(fmaf(acc[m][0].w, ndr, bb0.w), 0.f);
            o1.x = fmaxf(fmaf(acc[m][1].x, ndr, bb1.x), 0.f);
            o1.y = fmaxf(fmaf(acc[m][1].y, ndr, bb1.y), 0.f);
            o1.z = fmaxf(fmaf(acc[m][1].z, ndr, bb1.z), 0.f);
            o1.w = fmaxf(fmaf(acc[m][1].w, ndr, bb1.w), 0.f);
            if (SCALE_NS) {
                float s = ns[gr];
                o0.x *= s; o0.y *= s; o0.z *= s; o0.w *= s;
                o1.x *= s; o1.y *= s; o1.z *= s; o1.w *= s;
            }
            ((int4*)out)[(size_t)os * N * 2 + (size_t)gr * 2 + oh] = pack_h8(o0, o1);
        }
    }
}

// ---------------- GEMM 128(slab fp16) -> 40, *ns, output 5 slabs of int4 (8 halves) ----------

__global__ __launch_bounds__(256) void gemm40_kernel(const __half* __restrict__ A, const float* __restrict__ W,
                                                     const float* __restrict__ ns, __half* __restrict__ y, int N) {
    __shared__ float Ws[128 * NCLS];   // 20 KB
    __shared__ float As[32 * 132];     // 16.5 KB
    __shared__ __half ys[32][40];      // 2.5 KB
    int t = threadIdx.x;
    int row0 = blockIdx.x * 32;

#pragma unroll
    for (int i = 0; i < 5; ++i) {
        int idx = t + 256 * i;
        ((float4*)Ws)[idx] = ((const float4*)W)[idx];
    }
#pragma unroll
    for (int i = 0; i < 2; ++i) {
        int idx = t + 256 * i;        // 0..511
        int s = idx >> 6;
        int rem = idx & 63;
        int r = rem >> 1;
        int h = rem & 1;
        int gr = row0 + r;
        int4 v = make_int4(0, 0, 0, 0);
        if (gr < N) v = ((const int4*)A)[(size_t)s * N * 2 + (size_t)gr * 2 + h];
        const __half2* hh = (const __half2*)&v;
        float2 f0 = __half22float2(hh[0]);
        float2 f1 = __half22float2(hh[1]);
        float2 f2 = __half22float2(hh[2]);
        float2 f3 = __half22float2(hh[3]);
        float* dp = &As[r * 132 + (s * 2 + h) * 8];
        dp[0] = f0.x; dp[1] = f0.y; dp[2] = f1.x; dp[3] = f1.y;
        dp[4] = f2.x; dp[5] = f2.y; dp[6] = f3.x; dp[7] = f3.y;
    }
    __syncthreads();

    int row = t >> 3;
    int cg = t & 7;
    float acc[5] = {0.f, 0.f, 0.f, 0.f, 0.f};
#pragma unroll 2
    for (int k4 = 0; k4 < 32; ++k4) {
        float4 a = *(const float4*)&As[row * 132 + k4 * 4];
#pragma unroll
        for (int j = 0; j < 4; ++j) {
            float av = (j == 0) ? a.x : (j == 1) ? a.y : (j == 2) ? a.z : a.w;
            const float* wp = &Ws[(k4 * 4 + j) * NCLS + cg * 5];
            acc[0] = fmaf(av, wp[0], acc[0]);
            acc[1] = fmaf(av, wp[1], acc[1]);
            acc[2] = fmaf(av, wp[2], acc[2]);
            acc[3] = fmaf(av, wp[3], acc[3]);
            acc[4] = fmaf(av, wp[4], acc[4]);
        }
    }
    {
        int gr = row0 + row;
        float s = (gr < N) ? ns[gr] : 0.f;
        __half* yp = &ys[row][cg * 5];
        yp[0] = __float2half_rn(acc[0] * s);
        yp[1] = __float2half_rn(acc[1] * s);
        yp[2] = __float2half_rn(acc[2] * s);
        yp[3] = __float2half_rn(acc[3] * s);
        yp[4] = __float2half_rn(acc[4] * s);
    }
    __syncthreads();
    if (t < 160) {
        int s = t >> 5;      // 0..4
        int r = t & 31;
        int gr = row0 + r;
        if (gr < N) ((int4*)y)[(size_t)s * N + gr] = *(const int4*)&ys[r][s * 8];
    }
}

// ---------------- slab gather 40-d + *nd + b2 -> out (fp32) ----------------
// grid = nrb256*8; slice = bid&7 (XCD-pinned; slices 5-7 idle). Slab = 1.6 MB, L2-resident.

__global__ __launch_bounds__(256) void gather40f(const __half* __restrict__ y, const int* __restrict__ csr,
                                                 const int* __restrict__ cursor, const float* __restrict__ nd,
                                                 const float* __restrict__ b2, float* __restrict__ out, int N) {
    int bid = blockIdx.x;
    int slice = bid & 7;
    if (slice >= 5) return;
    int rb = bid >> 3;
    int r = rb * 256 + threadIdx.x;
    if (r >= N) return;
    const int4* ys = (const int4*)y + (size_t)slice * N;
    int start = cursor[r];
    int end = cursor[r + 1];
    float4 a0 = zero4(), a1 = zero4();
    int e = start;
    for (; e + 4 <= end; e += 4) {
        int i0 = csr[e + 0], i1 = csr[e + 1], i2 = csr[e + 2], i3 = csr[e + 3];
        int4 v0 = ys[i0];
        int4 v1 = ys[i1];
        int4 v2 = ys[i2];
        int4 v3 = ys[i3];
        add_h8(a0, a1, v0); add_h8(a0, a1, v1);
        add_h8(a0, a1, v2); add_h8(a0, a1, v3);
    }
    for (; e < end; ++e) {
        int4 v0 = ys[csr[e]];
        add_h8(a0, a1, v0);
    }
    float s = nd[r];
    const float* bp = b2 + slice * 8;
    float4 o0, o1;
    o0.x = fmaf(a0.x, s, bp[0]); o0.y = fmaf(a0.y, s, bp[1]);
    o0.z = fmaf(a0.z, s, bp[2]); o0.w = fmaf(a0.w, s, bp[3]);
    o1.x = fmaf(a1.x, s, bp[4]); o1.y = fmaf(a1.y, s, bp[5]);
    o1.z = fmaf(a1.z, s, bp[6]); o1.w = fmaf(a1.w, s, bp[7]);
    float* op = out + (size_t)r * NCLS + slice * 8;
    *(float4*)(op + 0) = o0;
    *(float4*)(op + 4) = o1;
}

extern "C" void kernel_launch(void* const* d_in, const int* in_sizes, int n_in,
                              void* d_out, int out_size, void* d_ws, size_t ws_size,
                              hipStream_t stream) {
    const float* x  = (const float*)d_in[0];
    const int* src  = (const int*)d_in[1];
    const int* dst  = (const int*)d_in[2];
    const float* W0 = (const float*)d_in[3];
    const float* b0 = (const float*)d_in[4];
    const float* W1 = (const float*)d_in[5];
    const float* b1 = (const float*)d_in[6];
    const float* W2 = (const float*)d_in[7];
    const float* b2 = (const float*)d_in[8];
    float* out = (float*)d_out;

    int N = in_sizes[0] / IN_DIM;
    int E = in_sizes[1];

    float* base = (float*)d_ws;
    float* ns   = base;                       // N
    float* ndn  = base + (size_t)N;           // N
    int* dsg    = (int*)(base + 2 * (size_t)N);
    int* ddg    = dsg + (size_t)N;
    int* cursor = ddg + (size_t)N;            // N+1
    int* bsums  = cursor + (size_t)N + 1;     // 1024
    int* csr    = bsums + 1024;               // E
    __half* B0  = (__half*)(csr + (size_t)E); // N x 128 halves (slabs)
    __half* B1  = B0 + (size_t)N * 128;       // N x 128 halves (slabs)
    __half* B2  = B1 + (size_t)N * 128;       // N x 128 halves (slabs)
    __half* yh  = B2 + (size_t)N * 128;       // 5 slabs x N int4
    int* staging = (int*)B1;                  // 8*HB*SLICE_MAX ints, dead before B1 is written

    int nb = (N + 1023) / 1024;
    int gN = (N + 255) / 256;

    // degrees via sliced LDS histograms (no global atomics)
    hist_sliced<<<8 * HB, 256, 0, stream>>>(src, staging, E, N);
    reduce_staging<0><<<gN, 256, 0, stream>>>(staging, dsg, N);
    hist_sliced<<<8 * HB, 256, 0, stream>>>(dst, staging, E, N);
    reduce_staging<1><<<gN, 256, 0, stream>>>(staging, ddg, N);   // + exclusive prefix scanback
    norm_kernel<<<gN, 256, 0, stream>>>(dsg, ddg, ns, ndn, N);

    // row starts
    scan_partial<<<nb, 256, 0, stream>>>(ddg, bsums, N);
    scan_bsums<<<1, 128, 0, stream>>>(bsums, nb);
    scan_final<<<nb, 256, 0, stream>>>(ddg, bsums, cursor, N);

    // CSR fill: LDS cursors, plain csr stores
    fill_noatomic<<<8 * HB, 256, 0, stream>>>(src, dst, cursor, staging, csr, E, N);

    // B0 = slabbed fp16(x * ns)
    prescale_kernel<<<(N * 16 + 255) / 256, 256, 0, stream>>>(x, ns, B0, N);

    int g64 = (N + 63) / 64;
    int nrb128 = (N + 127) / 128;
    int nrb256 = (N + 255) / 256;

    // layer 0: B1 = spmm(B0) ; B2 = relu(B1*nd @ W0 + b0)*ns   (all slabbed)
    spmm16s<<<nrb128 * 8, 256, 0, stream>>>(B0, csr, cursor, B1, N);
    gemm128h<1><<<g64, 256, 0, stream>>>(B1, ndn, ns, W0, b0, B2, N);

    // layer 1: B1 = spmm(B2) ; B0 = relu(B1*nd @ W1 + b1)
    spmm16s<<<nrb128 * 8, 256, 0, stream>>>(B2, csr, cursor, B1, N);
    gemm128h<0><<<g64, 256, 0, stream>>>(B1, ndn, ns, W1, b1, B0, N);

    // layer 2: yh = (B0 @ W2)*ns (5 slabs) ; out = gather40(yh)*nd + b2
    gemm40_kernel<<<(N + 31) / 32, 256, 0, stream>>>(B0, W2, ns, yh, N);
    gather40f<<<nrb256 * 8, 256, 0, stream>>>(yh, csr, cursor, ndn, b2, out, N);
}